// Round 3
// baseline (91.207 us; speedup 1.0000x reference)
//
#include <hip/hip_runtime.h>
#include <math.h>

// Problem constants (from reference setup_inputs)
#define B   64
#define NJ  42
#define NP  16384
#define CHUNKS 8
#define PC  (NP / CHUNKS)   // 2048 points per block
#define TPB 256
#define PPT (PC / TPB)      // 8 points per thread
#define NPAIR (PPT / 2)     // 4 float2 pairs per thread
#define RSTRIDE 260         // row stride (floats): consecutive-lane writes conflict-free
#define NBLK (B * CHUNKS)   // 512 blocks

typedef float v2f __attribute__((ext_vector_type(2)));

// Fully fused: per-(b,chunk) chunk-min -> partial store -> last-arriving block
// does the cross-chunk min + sqrt + MSE finalize. Single dispatch.
__global__ __launch_bounds__(TPB) void sdl_fused_kernel(
    const float* __restrict__ joints,   // [B, NJ, 3]
    const float* __restrict__ pts,      // [B, NP, 3]
    const float* __restrict__ gt,       // [B*NJ]
    float* __restrict__ part,           // ws: [CHUNKS][B*NJ] partial clamped d^2
    unsigned int* __restrict__ counter, // ws: ticket counter (poison-tolerant)
    float* __restrict__ out)            // [1]
{
    __shared__ __align__(16) float4 sj[NJ];               // joint xyz + |a|^2
    __shared__ __align__(16) float  red[NJ * RSTRIDE];    // transpose reduction scratch
    __shared__ int is_last;

    const int tid = threadIdx.x;
    const int b   = blockIdx.x >> 3;    // / CHUNKS
    const int ch  = blockIdx.x & 7;     // % CHUNKS

    // Stage joints: xyz and |a|^2
    if (tid < NJ) {
        const float* jp = joints + (b * NJ + tid) * 3;
        float x = jp[0], y = jp[1], z = jp[2];
        sj[tid] = make_float4(x, y, z, fmaf(x, x, fmaf(y, y, z * z)));
    }

    // Load 8 points/thread as 4 float2 pairs: NEGATED coords and q = 0.5*|p|^2
    // so the inner loop is a pure 3-FMA chain: q - a.p
    v2f npx[NPAIR], npy[NPAIR], npz[NPAIR], q[NPAIR];
    const float* pb = pts + (size_t)(b * NP + ch * PC) * 3;
#pragma unroll
    for (int k = 0; k < NPAIR; ++k) {
        int i0 = ((2 * k)     * TPB + tid) * 3;   // coalesced k-slices
        int i1 = ((2 * k + 1) * TPB + tid) * 3;
        float x0 = pb[i0], y0 = pb[i0 + 1], z0 = pb[i0 + 2];
        float x1 = pb[i1], y1 = pb[i1 + 1], z1 = pb[i1 + 2];
        npx[k] = (v2f){-x0, -x1};
        npy[k] = (v2f){-y0, -y1};
        npz[k] = (v2f){-z0, -z1};
        q[k]   = (v2f){0.5f * fmaf(x0, x0, fmaf(y0, y0, z0 * z0)),
                       0.5f * fmaf(x1, x1, fmaf(y1, y1, z1 * z1))};
    }
    __syncthreads();

    // Per-thread running min of (q - a.p) per joint.
    float m[NJ];
#pragma unroll
    for (int j = 0; j < NJ; ++j) m[j] = 3.0e38f;

#pragma unroll
    for (int j = 0; j < NJ; ++j) {
        float4 Jv = sj[j];                 // broadcast ds_read_b128
        v2f jx = (v2f){Jv.x, Jv.x};
        v2f jy = (v2f){Jv.y, Jv.y};
        v2f jz = (v2f){Jv.z, Jv.z};
        float mj = m[j];
#pragma unroll
        for (int k = 0; k < NPAIR; ++k) {
            v2f t = npz[k] * jz + q[k];    // v_pk_fma_f32
            t     = npy[k] * jy + t;
            t     = npx[k] * jx + t;
            mj = fminf(fminf(mj, t.x), t.y);   // -> v_min3_f32
        }
        m[j] = mj;
    }

    // Block reduction via LDS transpose (conflict-free column writes).
#pragma unroll
    for (int j = 0; j < NJ; ++j) red[j * RSTRIDE + tid] = m[j];
    __syncthreads();

    if (tid < NJ) {
        const float4* row = (const float4*)(red + tid * RSTRIDE);
        float4 a = row[0];
        for (int i = 1; i < TPB / 4; ++i) {
            float4 v = row[i];
            a.x = fminf(a.x, v.x); a.y = fminf(a.y, v.y);
            a.z = fminf(a.z, v.z); a.w = fminf(a.w, v.w);
        }
        float mn = fminf(fminf(a.x, a.y), fminf(a.z, a.w));
        float d2 = fmaxf(fmaf(2.0f, mn, sj[tid].w), 0.0f);
        part[ch * (B * NJ) + b * NJ + tid] = d2;
        __threadfence();                   // release: partials visible device-wide
    }
    __syncthreads();

    // Ticket: last-arriving block finalizes. Poison-tolerant: counter starts at
    // 0 (pristine) or 0xAAAAAAAA (harness 0xAA poison); we restore it after.
    if (tid == 0) {
        unsigned int old = __hip_atomic_fetch_add(counter, 1u,
                              __ATOMIC_ACQ_REL, __HIP_MEMORY_SCOPE_AGENT);
        is_last = (old == (NBLK - 1u)) || (old == 0xAAAAAAAAu + (NBLK - 1u));
    }
    __syncthreads();

    if (is_last) {
        __threadfence();                   // acquire: see all blocks' partials
        float acc = 0.0f;
        for (int i = tid; i < B * NJ; i += TPB) {
            float mn = part[i];
#pragma unroll
            for (int c = 1; c < CHUNKS; ++c) mn = fminf(mn, part[c * (B * NJ) + i]);
            float diff = sqrtf(mn) - gt[i];
            acc = fmaf(diff, diff, acc);
        }
#pragma unroll
        for (int off = 32; off > 0; off >>= 1)
            acc += __shfl_xor(acc, off);
        // reuse red[] for cross-wave sum (safe: past all other uses)
        if ((tid & 63) == 0) red[tid >> 6] = acc;
        __syncthreads();
        if (tid == 0) {
            out[0] = (red[0] + red[1] + red[2] + red[3]) * (1.0f / (B * NJ));
            // restore counter so the init value is call-invariant
            __hip_atomic_fetch_add(counter, (unsigned int)(0u - NBLK),
                                   __ATOMIC_RELAXED, __HIP_MEMORY_SCOPE_AGENT);
        }
    }
}

extern "C" void kernel_launch(void* const* d_in, const int* in_sizes, int n_in,
                              void* d_out, int out_size, void* d_ws, size_t ws_size,
                              hipStream_t stream) {
    const float* pred = (const float*)d_in[0];   // [B,NJ,3]
    const float* obj  = (const float*)d_in[1];   // [B,NP,3]
    const float* gt   = (const float*)d_in[2];   // [B,NJ]
    float* part = (float*)d_ws;                  // CHUNKS*B*NJ floats (86 KB)
    unsigned int* counter = (unsigned int*)d_ws + CHUNKS * B * NJ;

    sdl_fused_kernel<<<NBLK, TPB, 0, stream>>>(pred, obj, gt, part, counter,
                                               (float*)d_out);
}

// Round 4
// 72.713 us; speedup vs baseline: 1.2543x; 1.2543x over previous
//
#include <hip/hip_runtime.h>
#include <math.h>

// Problem constants (from reference setup_inputs)
#define B   64
#define NJ  42
#define NP  16384
#define CHUNKS 8
#define PC  (NP / CHUNKS)   // 2048 points per block
#define TPB 256
#define PPT (PC / TPB)      // 8 points per thread
#define NPAIR (PPT / 2)     // 4 float2 pairs per thread
#define RSTRIDE 260         // row stride (floats): consecutive-lane writes conflict-free
#define NQ  (B * NJ / 4)    // 672 float4 groups of (b,j) pairs

typedef float v2f __attribute__((ext_vector_type(2)));

// Per-(b,chunk) block: min over its 2048 points of (0.5*|p|^2 - a.p) for all
// 42 joints, finalized to clamped d^2 and stored as a partial (no atomics,
// no device-scope fences — R3 showed agent-scope release = buffer_wbl2 per
// block, an ~18 us regression).
__global__ __launch_bounds__(TPB) void sdl_min_kernel(
    const float* __restrict__ joints,   // [B, NJ, 3]
    const float* __restrict__ pts,      // [B, NP, 3]
    float* __restrict__ part)           // [CHUNKS][B*NJ] partial clamped d^2
{
    __shared__ __align__(16) float4 sj[NJ];               // joint xyz + |a|^2
    __shared__ __align__(16) float  red[NJ * RSTRIDE];    // transpose reduction scratch

    const int tid = threadIdx.x;
    const int b   = blockIdx.x >> 3;    // / CHUNKS
    const int ch  = blockIdx.x & 7;     // % CHUNKS

    // Stage joints: xyz and |a|^2
    if (tid < NJ) {
        const float* jp = joints + (b * NJ + tid) * 3;
        float x = jp[0], y = jp[1], z = jp[2];
        sj[tid] = make_float4(x, y, z, fmaf(x, x, fmaf(y, y, z * z)));
    }

    // Load 8 points/thread as 4 float2 pairs: NEGATED coords and q = 0.5*|p|^2
    // so the inner loop is a pure 3-FMA chain: q - a.p
    v2f npx[NPAIR], npy[NPAIR], npz[NPAIR], q[NPAIR];
    const float* pb = pts + (size_t)(b * NP + ch * PC) * 3;
#pragma unroll
    for (int k = 0; k < NPAIR; ++k) {
        int i0 = ((2 * k)     * TPB + tid) * 3;   // coalesced k-slices
        int i1 = ((2 * k + 1) * TPB + tid) * 3;
        float x0 = pb[i0], y0 = pb[i0 + 1], z0 = pb[i0 + 2];
        float x1 = pb[i1], y1 = pb[i1 + 1], z1 = pb[i1 + 2];
        npx[k] = (v2f){-x0, -x1};
        npy[k] = (v2f){-y0, -y1};
        npz[k] = (v2f){-z0, -z1};
        q[k]   = (v2f){0.5f * fmaf(x0, x0, fmaf(y0, y0, z0 * z0)),
                       0.5f * fmaf(x1, x1, fmaf(y1, y1, z1 * z1))};
    }
    __syncthreads();

    // Per-thread running min of (q - a.p) per joint.
    float m[NJ];
#pragma unroll
    for (int j = 0; j < NJ; ++j) m[j] = 3.0e38f;

#pragma unroll
    for (int j = 0; j < NJ; ++j) {
        float4 Jv = sj[j];                 // broadcast ds_read_b128
        v2f jx = (v2f){Jv.x, Jv.x};
        v2f jy = (v2f){Jv.y, Jv.y};
        v2f jz = (v2f){Jv.z, Jv.z};
        float mj = m[j];
#pragma unroll
        for (int k = 0; k < NPAIR; ++k) {
            v2f t = npz[k] * jz + q[k];    // v_pk_fma_f32
            t     = npy[k] * jy + t;
            t     = npx[k] * jx + t;
            mj = fminf(fminf(mj, t.x), t.y);   // -> v_min3_f32
        }
        m[j] = mj;
    }

    // Block reduction via LDS transpose (conflict-free column writes).
#pragma unroll
    for (int j = 0; j < NJ; ++j) red[j * RSTRIDE + tid] = m[j];
    __syncthreads();

    if (tid < NJ) {
        const float4* row = (const float4*)(red + tid * RSTRIDE);
        float4 a = row[0];
        for (int i = 1; i < TPB / 4; ++i) {
            float4 v = row[i];
            a.x = fminf(a.x, v.x); a.y = fminf(a.y, v.y);
            a.z = fminf(a.z, v.z); a.w = fminf(a.w, v.w);
        }
        float mn = fminf(fminf(a.x, a.y), fminf(a.z, a.w));
        // d^2 = 2*min(q - a.p) + |a|^2, clamped (commutes with min)
        float d2 = fmaxf(fmaf(2.0f, mn, sj[tid].w), 0.0f);
        part[ch * (B * NJ) + b * NJ + tid] = d2;
    }
}

__global__ __launch_bounds__(1024) void sdl_final_kernel(
    const float4* __restrict__ part4,   // [CHUNKS][NQ] float4 view of partials
    const float4* __restrict__ gt4,     // [NQ] float4 view of gt
    float* __restrict__ out)            // [1]
{
    const int tid = threadIdx.x;
    float acc = 0.0f;
    if (tid < NQ) {                      // 672 < 1024: single pass, float4 loads
        float4 mn = part4[tid];
#pragma unroll
        for (int c = 1; c < CHUNKS; ++c) {
            float4 v = part4[c * NQ + tid];
            mn.x = fminf(mn.x, v.x); mn.y = fminf(mn.y, v.y);
            mn.z = fminf(mn.z, v.z); mn.w = fminf(mn.w, v.w);
        }
        float4 g = gt4[tid];
        float dx = sqrtf(mn.x) - g.x;
        float dy = sqrtf(mn.y) - g.y;
        float dz = sqrtf(mn.z) - g.z;
        float dw = sqrtf(mn.w) - g.w;
        acc = fmaf(dx, dx, fmaf(dy, dy, fmaf(dz, dz, dw * dw)));
    }
#pragma unroll
    for (int off = 32; off > 0; off >>= 1)
        acc += __shfl_xor(acc, off);
    __shared__ float wsum[16];
    if ((tid & 63) == 0) wsum[tid >> 6] = acc;
    __syncthreads();
    if (tid == 0) {
        float s = 0.0f;
#pragma unroll
        for (int w = 0; w < 16; ++w) s += wsum[w];
        out[0] = s * (1.0f / (B * NJ));
    }
}

extern "C" void kernel_launch(void* const* d_in, const int* in_sizes, int n_in,
                              void* d_out, int out_size, void* d_ws, size_t ws_size,
                              hipStream_t stream) {
    const float* pred = (const float*)d_in[0];   // [B,NJ,3]
    const float* obj  = (const float*)d_in[1];   // [B,NP,3]
    const float* gt   = (const float*)d_in[2];   // [B,NJ]
    float* part = (float*)d_ws;                  // CHUNKS*B*NJ floats (86 KB)

    sdl_min_kernel<<<B * CHUNKS, TPB, 0, stream>>>(pred, obj, part);
    sdl_final_kernel<<<1, 1024, 0, stream>>>((const float4*)part,
                                             (const float4*)gt, (float*)d_out);
}